// Round 18
// baseline (66.977 us; speedup 1.0000x reference)
//
#include <hip/hip_runtime.h>
#include <hip/hip_bf16.h>

#define NN 50000
#define NE 800000

typedef short short8 __attribute__((ext_vector_type(8)));
typedef float f32x4 __attribute__((ext_vector_type(4)));
typedef unsigned short ushort_t;

// ---- truncation-based bf16 hi/lo split helpers ----
static __device__ __forceinline__ unsigned bits(float f) { return __float_as_uint(f); }
static __device__ __forceinline__ float hi_f(float v) {
  return __uint_as_float(bits(v) & 0xFFFF0000u);
}
static __device__ __forceinline__ ushort_t hi_u(float v) { return (ushort_t)(bits(v) >> 16); }
static __device__ __forceinline__ unsigned pack_hi(float v0, float v1) {
  return (bits(v0) >> 16) | (bits(v1) & 0xFFFF0000u);
}
static __device__ __forceinline__ unsigned pack_lo(float v0, float v1) {
  float l0 = v0 - hi_f(v0), l1 = v1 - hi_f(v1);
  return (bits(l0) >> 16) | (bits(l1) & 0xFFFF0000u);
}

#define MFMA(a, b, c) __builtin_amdgcn_mfma_f32_16x16x32_bf16(a, b, c, 0, 0, 0)

// ---------------- kA: weight-pack hi-only (t < 4096) + CSR offsets (all threads).
__global__ __launch_bounds__(256) void kA_pack_off(
    const float* __restrict__ Wn, const float* __restrict__ Wc,
    const float* __restrict__ Wu, const float* __restrict__ base_w,
    const float* __restrict__ spline_w, const float* __restrict__ scaler,
    const int* __restrict__ seg,
    ushort_t* __restrict__ p1h, ushort_t* __restrict__ p2h,
    ushort_t* __restrict__ p3h, int* __restrict__ off) {
  int t = blockIdx.x * 256 + threadIdx.x;
  if (t < 4096) {
    int l = t & 63, lm = l & 15, lk = l >> 4;
    if (t < 2048) {
      int nt = t >> 8, ks = (t >> 6) & 3;
      int h = nt * 16 + lm;
#pragma unroll
      for (int j = 0; j < 8; ++j) {
        int f = ks * 32 + lk * 8 + j;
        float v = (f < 64) ? Wn[h * 64 + f] : Wc[h * 64 + (f - 64)];
        p1h[t * 8 + j] = hi_u(v);
      }
    }
    if (t < 1024) {
      int nt = t >> 8, ks = (t >> 6) & 3;
      int o = nt * 16 + lm;
#pragma unroll
      for (int j = 0; j < 8; ++j) {
        int hh = ks * 32 + lk * 8 + j;
        p2h[t * 8 + j] = hi_u(Wu[o * 128 + hh]);
      }
    }
    if (t < 3072) {
      int nt = t / 768, ks = (t >> 6) % 12;
      int o = nt * 16 + lm;
#pragma unroll
      for (int j = 0; j < 8; ++j) {
        int k = ks * 32 + lk * 8 + j;
        int i = k / 6, c = k % 6;
        float v = (c == 0) ? base_w[o * 64 + i]
                           : spline_w[(o * 64 + i) * 5 + (c - 1)] * scaler[o * 64 + i];
        p3h[t * 8 + j] = hi_u(v);
      }
    }
  }
  int e = t;
  if (e < NE) {
    int s1 = seg[e];
    if (e == 0) {
      for (int n = 0; n <= s1; ++n) off[n] = 0;
    } else {
      int s0 = seg[e - 1];
      for (int n = s0 + 1; n <= s1; ++n) off[n] = e;
    }
    if (e == NE - 1) {
      for (int n = s1 + 1; n <= NN; ++n) off[n] = NE;
    }
  }
}

// ---------------- k1234: fused edge-agg + 3-GEMM pipeline. 64-node tile, 512 thr (8 waves, 2Mx4N).
// Sp never touches global: edge phase writes bf16-hi straight into U's cols 64..127.
// Byte diet: x hi+lo (lo used for ks<2 only), coalesced out via LDS ot tile.
// Arena 48KB: Uh[64][128] | Ul[64][128] | Th[64][128]; V [32][384] overlays Uh+Ul head;
// ot [32][64] f32 overlays Ul tail. 6 barriers.
__global__ __launch_bounds__(512, 3) void k1234(
    const float* __restrict__ x,
    const float* __restrict__ contexts, const float* __restrict__ attn,
    const int* __restrict__ off,
    const float* __restrict__ bn, const float* __restrict__ bc,
    const float* __restrict__ bu,
    const ushort_t* __restrict__ p1h, const ushort_t* __restrict__ p2h,
    const ushort_t* __restrict__ p3h,
    const float* __restrict__ gridp, float* __restrict__ out) {
  __shared__ __align__(16) unsigned char arena[49152];
  __shared__ float ap[64], degl[64];
  ushort_t* Uh = (ushort_t*)arena;             // [64][128] swizzled (hi: x | Sp)
  ushort_t* Ul = (ushort_t*)(arena + 16384);   // [64][128] swizzled (x-lo cols 0..63 only)
  ushort_t* Th = (ushort_t*)(arena + 32768);   // [64][128] swizzled (T hi)
  ushort_t* Vh = (ushort_t*)arena;             // [32][384] per-uint XOR swizzle
  float*    ot = (float*)(arena + 24576);      // [32][64] f32 XOR swizzle (Ul tail)

  int tid = threadIdx.x;
  int n0 = blockIdx.x * 64;
  int w = tid >> 6, l = tid & 63;
  int wm = w >> 2, wn = w & 3;
  int lm = l & 15, lk = l >> 4;
  const short8* P1h = (const short8*)p1h;
  const short8* P2h = (const short8*)p2h;
  const short8* P3h = (const short8*)p3h;

  // ---- phase X: stage x (cols 0..63) hi+lo, swizzled. One pass (512 thr).
  {
    const float4* x4 = (const float4*)x;
    int row = tid >> 3, slot = tid & 7;
    int n = n0 + row;
    float4 a = make_float4(0.f, 0.f, 0.f, 0.f), b = a;
    if (n < NN) {
      a = x4[(size_t)n * 16 + slot * 2];
      b = x4[(size_t)n * 16 + slot * 2 + 1];
    }
    uint4 hp, lp;
    hp.x = pack_hi(a.x, a.y); hp.y = pack_hi(a.z, a.w);
    hp.z = pack_hi(b.x, b.y); hp.w = pack_hi(b.z, b.w);
    lp.x = pack_lo(a.x, a.y); lp.y = pack_lo(a.z, a.w);
    lp.z = pack_lo(b.x, b.y); lp.w = pack_lo(b.z, b.w);
    int idx = (row * 128 + slot * 8) ^ ((row & 7) << 3);
    *(uint4*)&Uh[idx] = hp;
    *(uint4*)&Ul[idx] = lp;
  }

  // ---- phase E: edge aggregation, wave w -> nodes [n0+w*8, n0+w*8+8). Sp-hi -> Uh cols 64..127.
  {
    int nb = n0 + w * 8;
    int offv = 0;
    if (l < 9) offv = off[min(nb + l, NN)];
    int sub = l >> 4, fq = l & 15;
    const float4* ctx4 = (const float4*)contexts;
#pragma unroll 1
    for (int i = 0; i < 8; ++i) {
      int s = __shfl(offv, i);
      int e_end = __shfl(offv, i + 1);
      int deg_i = e_end - s;
      float4 S = make_float4(0.f, 0.f, 0.f, 0.f);
      float A = 0.f;
      if (deg_i > 0) {
        int last = e_end - 1;
        for (int e0 = s; e0 < e_end; e0 += 16) {
          float a[4];
          float4 c[4];
#pragma unroll
          for (int u = 0; u < 4; ++u) {
            int eu = e0 + 4 * u + sub;
            a[u] = (eu < e_end) ? attn[eu] : 0.f;
            c[u] = ctx4[(size_t)min(eu, last) * 16 + fq];
          }
#pragma unroll
          for (int u = 0; u < 4; ++u) {
            S.x += a[u] * c[u].x;
            S.y += a[u] * c[u].y;
            S.z += a[u] * c[u].z;
            S.w += a[u] * c[u].w;
            A += a[u];
          }
        }
      }
#pragma unroll
      for (int m = 16; m <= 32; m <<= 1) {
        S.x += __shfl_xor(S.x, m);
        S.y += __shfl_xor(S.y, m);
        S.z += __shfl_xor(S.z, m);
        S.w += __shfl_xor(S.w, m);
        A += __shfl_xor(A, m);
      }
      float deg = (float)deg_i;
      float inv = 1.f / fmaxf(deg, 1.f);
      int row = w * 8 + i;
      if (l < 16) {
        float ox = S.x * inv, oy = S.y * inv, oz = S.z * inv, ow = S.w * inv;
        uint2 hp;
        hp.x = pack_hi(ox, oy);
        hp.y = pack_hi(oz, ow);
        int idx = (row * 128 + 64 + l * 4) ^ ((row & 7) << 3);
        *(uint2*)&Uh[idx] = hp;
      }
      if (l == 0) { ap[row] = A * inv; degl[row] = deg; }
    }
  }

  // ---- hoist GEMM2 B-fragments (latency overlaps barrier)
  short8 B2[4];
#pragma unroll
  for (int ks = 0; ks < 4; ++ks) B2[ks] = P2h[(wn * 4 + ks) * 64 + l];

  __syncthreads();  // A: U tile complete

  int swzA = (lm & 7) << 3;

  // ---- GEMM1: m-tiles {2wm,2wm+1} x h-tiles {2wn,2wn+1}. hi all K, x-lo for ks<2. B1 from L2.
  f32x4 acc1[2][2];  // [q=h-tile][ms=m-tile]
#pragma unroll
  for (int q = 0; q < 2; ++q)
#pragma unroll
    for (int ms = 0; ms < 2; ++ms) acc1[q][ms] = (f32x4){0.f, 0.f, 0.f, 0.f};
#pragma unroll
  for (int ks = 0; ks < 4; ++ks) {
    short8 bh0 = P1h[((2 * wn + 0) * 4 + ks) * 64 + l];
    short8 bh1 = P1h[((2 * wn + 1) * 4 + ks) * 64 + l];
#pragma unroll
    for (int ms = 0; ms < 2; ++ms) {
      int ai = (((2 * wm + ms) * 16 + lm) * 128 + ks * 32 + lk * 8) ^ swzA;
      short8 ah = *(const short8*)&Uh[ai];
      acc1[0][ms] = MFMA(ah, bh0, acc1[0][ms]);
      acc1[1][ms] = MFMA(ah, bh1, acc1[1][ms]);
      if (ks < 2) {  // x-lo contribution only
        short8 al = *(const short8*)&Ul[ai];
        acc1[0][ms] = MFMA(al, bh0, acc1[0][ms]);
        acc1[1][ms] = MFMA(al, bh1, acc1[1][ms]);
      }
    }
  }
  // bias + T-write (hi-only) into Th
#pragma unroll
  for (int q = 0; q < 2; ++q) {
    int h = (2 * wn + q) * 16 + lm;
    float bnv = bn[h], bcv = bc[h];
#pragma unroll
    for (int ms = 0; ms < 2; ++ms) {
#pragma unroll
      for (int r = 0; r < 4; ++r) {
        int node = (2 * wm + ms) * 16 + lk * 4 + r;
        float t = acc1[q][ms][r] + bnv + ap[node] * bcv;
        Th[(node * 128 + h) ^ ((node & 7) << 3)] = hi_u(t);
      }
    }
  }
  __syncthreads();  // B: GEMM1 reads done, T ready

  // ---- spline constants + bu (hide under GEMM2)
  float g[8];
#pragma unroll
  for (int j = 0; j < 8; ++j) g[j] = gridp[j];
  float r1[7], r2[6];
#pragma unroll
  for (int j = 0; j < 7; ++j) r1[j] = 1.f / (g[j + 1] - g[j]);
#pragma unroll
  for (int j = 0; j < 6; ++j) r2[j] = 1.f / (g[j + 2] - g[j]);
  float buv = bu[wn * 16 + lm];

  // ---- GEMM2 (1-term): m-tiles {2wm,2wm+1} x o-tile wn. K=128.
  f32x4 acc2[2];
  acc2[0] = (f32x4){0.f, 0.f, 0.f, 0.f};
  acc2[1] = (f32x4){0.f, 0.f, 0.f, 0.f};
#pragma unroll
  for (int ks = 0; ks < 4; ++ks) {
#pragma unroll
    for (int ms = 0; ms < 2; ++ms) {
      int ai = (((2 * wm + ms) * 16 + lm) * 128 + ks * 32 + lk * 8) ^ swzA;
      short8 ah = *(const short8*)&Th[ai];
      acc2[ms] = MFMA(ah, B2[ks], acc2[ms]);
    }
  }
  // (no barrier: Vh overlays Uh/Ul whose last reads were before barrier B; GEMM2 reads Th only)

  // ---- two 32-node halves: transform (owning waves) -> Vh, KAN+ot, copy-out
#pragma unroll
  for (int half = 0; half < 2; ++half) {
    if (wm == half) {
#pragma unroll
      for (int ms = 0; ms < 2; ++ms) {
#pragma unroll
        for (int r = 0; r < 4; ++r) {
          float xv = acc2[ms][r] + buv;
          float sil = xv / (1.f + __expf(-xv));
          float b0[7], b1[6], b2[5];
#pragma unroll
          for (int q = 0; q < 7; ++q) b0[q] = (xv >= g[q] && xv < g[q + 1]) ? 1.f : 0.f;
#pragma unroll
          for (int q = 0; q < 6; ++q)
            b1[q] = (xv - g[q]) * r1[q] * b0[q] + (g[q + 2] - xv) * r1[q + 1] * b0[q + 1];
#pragma unroll
          for (int q = 0; q < 5; ++q)
            b2[q] = (xv - g[q]) * r2[q] * b1[q] + (g[q + 3] - xv) * r2[q + 1] * b1[q + 1];
          int ln = ms * 16 + lk * 4 + r;
          int base = ln * 384 + (wn * 16 + lm) * 6;
          int sw = (ln & 7) << 3;
          *(unsigned*)&Vh[(base + 0) ^ sw] = pack_hi(sil, b2[0]);
          *(unsigned*)&Vh[(base + 2) ^ sw] = pack_hi(b2[1], b2[2]);
          *(unsigned*)&Vh[(base + 4) ^ sw] = pack_hi(b2[3], b2[4]);
        }
      }
    }
    __syncthreads();  // V ready (also: prev half's ot reads complete)

    // KAN GEMM (1-term): o-tile wn, row-tile wm. K=384. B3 from L2. ot-store (disjoint region).
    f32x4 accK = (f32x4){0.f, 0.f, 0.f, 0.f};
#pragma unroll
    for (int ks = 0; ks < 12; ++ks) {
      short8 bh = P3h[(wn * 12 + ks) * 64 + l];
      int ri = ((wm * 16 + lm) * 384 + ks * 32 + lk * 8) ^ swzA;
      short8 ah = *(const short8*)&Vh[ri];
      accK = MFMA(ah, bh, accK);
    }
    {
      int o = wn * 16 + lm;
#pragma unroll
      for (int r = 0; r < 4; ++r) {
        int ln = wm * 16 + lk * 4 + r;
        ot[(ln * 64 + o) ^ ((ln & 7) << 3)] = accK[r];
      }
    }
    __syncthreads();  // O: ot writes + all Vh reads done

    // coalesced copy-out: 16 threads x 16B per row, full 256B lines
    {
      int row2 = tid >> 4, c4 = (tid & 15) * 4;
      int node = half * 32 + row2;
      int n = n0 + node;
      if (n < NN) {
        int sw = (row2 & 7) << 3;
        float4 v0 = *(float4*)&ot[((row2 * 64 + c4) ^ sw)];
        if (degl[node] <= 0.f) {
          v0 = *(const float4*)(x + (size_t)n * 64 + c4);
        }
        *(float4*)(out + (size_t)n * 64 + c4) = v0;
      }
    }
    // next half's transform (wm==1 waves) + this copy both follow barrier O; they touch
    // disjoint regions (Vh vs ot/out). Barrier V of next half orders copy vs ot re-write.
  }
}

extern "C" void kernel_launch(void* const* d_in, const int* in_sizes, int n_in,
                              void* d_out, int out_size, void* d_ws, size_t ws_size,
                              hipStream_t stream) {
  const float* x        = (const float*)d_in[0];
  const float* contexts = (const float*)d_in[1];
  const float* attn     = (const float*)d_in[2];
  const int*   seg      = (const int*)d_in[3];
  const float* Wn       = (const float*)d_in[4];
  const float* bn       = (const float*)d_in[5];
  const float* Wc       = (const float*)d_in[6];
  const float* bc       = (const float*)d_in[7];
  const float* Wu       = (const float*)d_in[8];
  const float* bu       = (const float*)d_in[9];
  const float* base_w   = (const float*)d_in[10];
  const float* spline_w = (const float*)d_in[11];
  const float* scaler   = (const float*)d_in[12];
  const float* gridp    = (const float*)d_in[13];
  float* out = (float*)d_out;

  ushort_t* us  = (ushort_t*)d_ws;
  ushort_t* p1h = us;                    // 16384
  ushort_t* p2h = p1h + 16384;           // 8192
  ushort_t* p3h = p2h + 8192;            // 24576
  int*   off    = (int*)(p3h + 24576);   // 50,001

  kA_pack_off<<<3125, 256, 0, stream>>>(Wn, Wc, Wu, base_w, spline_w, scaler, seg,
                                        p1h, p2h, p3h, off);
  k1234<<<782, 512, 0, stream>>>(x, contexts, attn, off, bn, bc, bu,
                                 p1h, p2h, p3h, gridp, out);
}